// Round 13
// baseline (525.784 us; speedup 1.0000x reference)
//
#include <hip/hip_runtime.h>
#include <hip/hip_cooperative_groups.h>
#include <math.h>

namespace cg = cooperative_groups;

#define B_    32
#define CIN   16
#define T_    2048
#define NG    8
#define CPG   16
#define HID   128
#define KW    5
#define EPS_  1e-5f

#define NROW  2080   // xT rows r = t+2; rows 0,1 and 2050..2079 zero
#define ROWS  16     // shorts per row (= CIN) -> 32B rows
#define NH    2      // T halves
#define QT    1024   // t per block
#define QROWS 1032   // staged rows per half (1024 + halo/pad)

// ws layout: shorts
#define SH_EWF  1064960          // [es(0=sh,1..8)][g][p<3][l<64][8]
#define SH_RWF  1175552          // [g][p<3][l<64][8]
// floats (byte 2,375,680 onward)
#define FO_GW   593920           // gate weights [64]
#define FO_GI   593984           // gate indices [64] (ints)
#define FO_STR  594048           // router stats [(b*8+g)][8] float2
#define FO_STSH 598144           // shared stats [(b*8+g)][8] float2
#define FO_STE  602240           // expert stats [(b*8+g)*2+sl][8] float2
#define FO_GAP  610432           // gap [b*128+co][8]

typedef float f32x4 __attribute__((ext_vector_type(4)));
typedef short s16x8 __attribute__((ext_vector_type(8)));

__device__ __forceinline__ float gelu_fast(float y) {
    float p = y * y;
    float u = y * (0.7978845608028654f + 0.03567740813636141f * p);
    float au = fabsf(u);
    float e = __expf(2.0f * au);
    float th = copysignf(1.0f - 2.0f * __builtin_amdgcn_rcpf(e + 1.0f), u);
    return 0.5f * y * (1.0f + th);
}

__device__ __forceinline__ float gelu_sig(float y) {
    float e = __expf(-1.702f * y);
    return y * __builtin_amdgcn_rcpf(1.0f + e);
}

__device__ __forceinline__ float gelu_erf(float y) {
    return 0.5f * y * (1.0f + erff(y * 0.70710678118654752440f));
}

__device__ __forceinline__ short bf16r(float f) {
    unsigned u = __builtin_bit_cast(unsigned, f);
    u = u + 0x7FFFu + ((u >> 16) & 1u);
    return (short)(u >> 16);
}

__device__ __forceinline__ void ldafr(const short* __restrict__ wb, int l,
                                      s16x8* a)
{
    a[0] = *(const s16x8*)(wb + (0 * 64 + l) * 8);
    a[1] = *(const s16x8*)(wb + (1 * 64 + l) * 8);
    a[2] = *(const s16x8*)(wb + (2 * 64 + l) * 8);
}

// ---------------------------------------------------------------------------
// Single cooperative kernel: prep -> router stats -> router GAP -> gate ->
// expert stats -> expert apply. Block = (b, g, half). LDS x-tile staged once.
// ---------------------------------------------------------------------------
__global__ __launch_bounds__(256, 4) void fused_kernel(
    const float* __restrict__ x, const float* __restrict__ rw,
    const float* __restrict__ ew, const float* __restrict__ sw,
    const float* __restrict__ rg, const float* __restrict__ rb,
    const float* __restrict__ demo,
    const float* __restrict__ m1w, const float* __restrict__ m1b,
    const float* __restrict__ lng, const float* __restrict__ lnb,
    const float* __restrict__ m2w, const float* __restrict__ m2b,
    const float* __restrict__ d1w, const float* __restrict__ d1b,
    const float* __restrict__ dlng, const float* __restrict__ dlnb,
    const float* __restrict__ d2w, const float* __restrict__ d2b,
    const float* __restrict__ gw, const float* __restrict__ gb,
    const float* __restrict__ eb, const float* __restrict__ eg,
    const float* __restrict__ ebt,
    const float* __restrict__ sb, const float* __restrict__ sg,
    const float* __restrict__ sbt,
    short* __restrict__ wsf, float* __restrict__ out)
{
    __shared__ short xs[QROWS * ROWS];
    __shared__ float sh[128];
    __shared__ float dd[32];
    __shared__ float rr[80];
    __shared__ float glds[8];
    __shared__ float redg[2], redq[2];

    cg::grid_group grid = cg::this_grid();

    const int b = blockIdx.x, g = blockIdx.y, h = blockIdx.z;
    const int fid = b + B_ * (g + NG * h);      // 0..511 flat id for P0
    const int tid = threadIdx.x;
    const int l = tid & 63, wv = tid >> 6;
    const int n = l & 15, grp = l >> 4;
    const int s_ = grp >> 1, cib = (grp & 1) * 8;

    float* wsff = (float*)wsf;
    float* gateW = wsff + FO_GW;
    int*   gateI = (int*)(wsff + FO_GI);
    float* str   = wsff + FO_STR;
    float* stsh  = wsff + FO_STSH;
    float* ste   = wsff + FO_STE;
    float* gap   = wsff + FO_GAP;

    // ================= P0: prep (transpose + weight frags) =================
    if (fid < 64) {
        const int pb = fid >> 1, ph = fid & 1;
        const float* xb = x + (size_t)pb * CIN * T_;
        short* xtb = wsf + (size_t)pb * NROW * ROWS;
        const int t0 = (ph * 256 + tid) * 4;
        float v[CIN][4];
        #pragma unroll
        for (int ci = 0; ci < CIN; ++ci)
            *(f32x4*)v[ci] = *(const f32x4*)(xb + ci * T_ + t0);
        #pragma unroll
        for (int tt = 0; tt < 4; ++tt) {
            s16x8 lo, hi;
            #pragma unroll
            for (int ci = 0; ci < 8; ++ci) lo[ci] = bf16r(v[ci][tt]);
            #pragma unroll
            for (int ci = 0; ci < 8; ++ci) hi[ci] = bf16r(v[ci + 8][tt]);
            short* rp = xtb + (size_t)(t0 + tt + 2) * ROWS;
            *(s16x8*)rp = lo;
            *(s16x8*)(rp + 8) = hi;
        }
        if (ph == 0 && tid < 32) {
            int r = (tid < 2) ? tid : 2048 + tid;
            s16x8 z = {0, 0, 0, 0, 0, 0, 0, 0};
            short* rp = xtb + (size_t)r * ROWS;
            *(s16x8*)rp = z;
            *(s16x8*)(rp + 8) = z;
        }
    } else if (fid < 144 && tid < 64) {
        const int id = fid - 64;
        const float* src;
        short* dst;
        if (id < 72) {
            int es = id / 8, gg = id - es * 8;
            src = ((es == 0) ? sw : ew + (size_t)(es - 1) * 128 * (CIN * KW))
                  + (size_t)gg * CPG * (CIN * KW);
            dst = wsf + SH_EWF + ((size_t)(es * 8 + gg) * 3) * 64 * 8;
        } else {
            int gg = id - 72;
            src = rw + (size_t)gg * CPG * (CIN * KW);
            dst = wsf + SH_RWF + ((size_t)gg * 3) * 64 * 8;
        }
        #pragma unroll
        for (int p = 0; p < 3; ++p) {
            int sht = 2 * p + s_;
            s16x8 a;
            if (sht < 5) {
                const float* wp = src + (size_t)n * (CIN * KW) + cib * KW + sht;
                #pragma unroll
                for (int j = 0; j < 8; ++j) a[j] = bf16r(wp[j * KW]);
            } else {
                #pragma unroll
                for (int j = 0; j < 8; ++j) a[j] = 0;
            }
            *(s16x8*)(dst + ((size_t)p * 64 + l) * 8) = a;
        }
    }
    __threadfence();
    grid.sync();

    // ================= P1: stage LDS; router + shared conv stats ===========
    {
        const s16x8* src = (const s16x8*)(wsf + ((size_t)b * NROW + h * QT) * ROWS);
        s16x8* dst = (s16x8*)xs;
        #pragma unroll
        for (int i = 0; i < 8; ++i)
            dst[tid + i * 256] = src[tid + i * 256];
        if (tid < 16) dst[tid + 2048] = src[tid + 2048];
    }
    {
        s16x8 afr_r[3], afr_s[3];
        ldafr(wsf + SH_RWF + ((size_t)g * 3) * 64 * 8, l, afr_r);
        ldafr(wsf + SH_EWF + ((size_t)(0 * 8 + g) * 3) * 64 * 8, l, afr_s);
        float biaS[4];
        #pragma unroll
        for (int r = 0; r < 4; ++r) biaS[r] = sb[g * CPG + grp * 4 + r];
        __syncthreads();

        float sR = 0.f, qR = 0.f, sS = 0.f, qS = 0.f;
        for (int tile = 0; tile < 16; ++tile) {
            const int t0 = (wv * 16 + tile) * 16;
            s16x8 bf0 = *(const s16x8*)&xs[(t0 + n + 0 + s_) * ROWS + cib];
            s16x8 bf1 = *(const s16x8*)&xs[(t0 + n + 2 + s_) * ROWS + cib];
            s16x8 bf2 = *(const s16x8*)&xs[(t0 + n + 4 + s_) * ROWS + cib];
            f32x4 cR = {0.f, 0.f, 0.f, 0.f};
            cR = __builtin_amdgcn_mfma_f32_16x16x32_bf16(afr_r[0], bf0, cR, 0, 0, 0);
            cR = __builtin_amdgcn_mfma_f32_16x16x32_bf16(afr_r[1], bf1, cR, 0, 0, 0);
            cR = __builtin_amdgcn_mfma_f32_16x16x32_bf16(afr_r[2], bf2, cR, 0, 0, 0);
            f32x4 cS = {0.f, 0.f, 0.f, 0.f};
            cS = __builtin_amdgcn_mfma_f32_16x16x32_bf16(afr_s[0], bf0, cS, 0, 0, 0);
            cS = __builtin_amdgcn_mfma_f32_16x16x32_bf16(afr_s[1], bf1, cS, 0, 0, 0);
            cS = __builtin_amdgcn_mfma_f32_16x16x32_bf16(afr_s[2], bf2, cS, 0, 0, 0);
            #pragma unroll
            for (int r = 0; r < 4; ++r) {
                sR += cR[r]; qR += cR[r] * cR[r];
                float v = cS[r] + biaS[r];
                sS += v; qS += v * v;
            }
        }
        for (int d = 1; d < 64; d <<= 1) {
            sR += __shfl_xor(sR, d); qR += __shfl_xor(qR, d);
            sS += __shfl_xor(sS, d); qS += __shfl_xor(qS, d);
        }
        if (l == 0) {
            int idx = (b * NG + g) * 8 + h * 4 + wv;
            str[idx * 2 + 0]  = sR; str[idx * 2 + 1]  = qR;
            stsh[idx * 2 + 0] = sS; stsh[idx * 2 + 1] = qS;
        }
    }
    __threadfence();
    grid.sync();

    // ================= P2: router GAP (conv recompute from hot LDS) ========
    {
        s16x8 afr_r[3];
        ldafr(wsf + SH_RWF + ((size_t)g * 3) * 64 * 8, l, afr_r);
        float S = 0.f, Q = 0.f;
        const float* sp = str + (size_t)(b * NG + g) * 16;
        for (int i = 0; i < 8; ++i) { S += sp[i * 2]; Q += sp[i * 2 + 1]; }
        const float inv_n = 1.0f / (CPG * T_);
        float mu = S * inv_n;
        float rs = rsqrtf(Q * inv_n - mu * mu + EPS_);
        float ka[4], kb[4];
        #pragma unroll
        for (int r = 0; r < 4; ++r) {
            int co = g * CPG + grp * 4 + r;
            float gm = rg[co];
            ka[r] = rs * gm;
            kb[r] = rb[co] - mu * rs * gm;
        }
        f32x4 tacc = {0.f, 0.f, 0.f, 0.f};
        for (int tile = 0; tile < 16; ++tile) {
            const int t0 = (wv * 16 + tile) * 16;
            s16x8 bf0 = *(const s16x8*)&xs[(t0 + n + 0 + s_) * ROWS + cib];
            s16x8 bf1 = *(const s16x8*)&xs[(t0 + n + 2 + s_) * ROWS + cib];
            s16x8 bf2 = *(const s16x8*)&xs[(t0 + n + 4 + s_) * ROWS + cib];
            f32x4 cc = {0.f, 0.f, 0.f, 0.f};
            cc = __builtin_amdgcn_mfma_f32_16x16x32_bf16(afr_r[0], bf0, cc, 0, 0, 0);
            cc = __builtin_amdgcn_mfma_f32_16x16x32_bf16(afr_r[1], bf1, cc, 0, 0, 0);
            cc = __builtin_amdgcn_mfma_f32_16x16x32_bf16(afr_r[2], bf2, cc, 0, 0, 0);
            #pragma unroll
            for (int r = 0; r < 4; ++r)
                tacc[r] += gelu_fast(cc[r] * ka[r] + kb[r]);
        }
        #pragma unroll
        for (int r = 0; r < 4; ++r)
            for (int d = 1; d < 16; d <<= 1)
                tacc[r] += __shfl_xor(tacc[r], d);
        if (n == 0) {
            #pragma unroll
            for (int r = 0; r < 4; ++r) {
                int co = g * CPG + grp * 4 + r;
                gap[(size_t)(b * HID + co) * 8 + h * 4 + wv] = tacc[r];
            }
        }
    }
    __threadfence();
    grid.sync();

    // ================= P3: gate (32 blocks, block-uniform guard) ===========
    if (g == 0 && h == 0) {
        const int j = tid;
        const int lane = j & 63, wvg = j >> 6;
        if (j < 128) {
            float a = 0.f;
            const float* gp = gap + (size_t)(b * HID + j) * 8;
            #pragma unroll
            for (int i = 0; i < 8; ++i) a += gp[i];
            sh[j] = a * (1.0f / T_);
        }
        __syncthreads();
        float gv = 0.f;
        if (j < 128) {
            float v = m1b[j];
            for (int i = 0; i < 128; ++i) v += sh[i] * m1w[j * 128 + i];
            float s = v, sq = v * v;
            for (int d = 1; d < 64; d <<= 1) { s += __shfl_xor(s, d); sq += __shfl_xor(sq, d); }
            if (lane == 0) { redg[wvg] = s; redq[wvg] = sq; }
            __syncthreads();
            float S = redg[0] + redg[1], SQ = redq[0] + redq[1];
            float mu = S * (1.f / 128.f), var = SQ * (1.f / 128.f) - mu * mu;
            float hh = (v - mu) * rsqrtf(var + EPS_) * lng[j] + lnb[j];
            gv = gelu_erf(hh);
        } else {
            __syncthreads();
        }
        __syncthreads();
        if (j < 128) sh[j] = gv;
        __syncthreads();
        if (j < 64) {
            float rv = m2b[j];
            for (int i = 0; i < 128; ++i) rv += sh[i] * m2w[j * 128 + i];
            rr[j] = rv;
        } else if (j < 96) {
            int jd = j - 64;
            float u = d1b[jd];
            for (int i = 0; i < 8; ++i) u += demo[b * 8 + i] * d1w[jd * 8 + i];
            float s2 = u, q2 = u * u;
            for (int d = 1; d < 32; d <<= 1) { s2 += __shfl_xor(s2, d, 32); q2 += __shfl_xor(q2, d, 32); }
            float mu2 = s2 * (1.f / 32.f), var2 = q2 * (1.f / 32.f) - mu2 * mu2;
            float y = (u - mu2) * rsqrtf(var2 + EPS_) * dlng[jd] + dlnb[jd];
            dd[jd] = gelu_erf(y);
        }
        __syncthreads();
        if (j < 16) {
            float rv = d2b[j];
            for (int i = 0; i < 32; ++i) rv += dd[i] * d2w[j * 32 + i];
            rr[64 + j] = rv;
        }
        __syncthreads();
        if (j < 8) {
            float lg = gb[j];
            for (int i = 0; i < 80; ++i) lg += rr[i] * gw[j * 80 + i];
            glds[j] = lg;
        }
        __syncthreads();
        if (j == 0) {
            float wsfm[8];
            float m = glds[0];
            for (int e = 1; e < 8; ++e) m = fmaxf(m, glds[e]);
            float ssum = 0.f;
            for (int e = 0; e < 8; ++e) { wsfm[e] = expf(glds[e] - m); ssum += wsfm[e]; }
            for (int e = 0; e < 8; ++e) wsfm[e] /= ssum;
            int i1 = 0;
            for (int e = 1; e < 8; ++e) if (wsfm[e] > wsfm[i1]) i1 = e;
            int i2 = (i1 == 0) ? 1 : 0;
            for (int e = 0; e < 8; ++e) if (e != i1 && wsfm[e] > wsfm[i2]) i2 = e;
            float aa = wsfm[i1], b2 = wsfm[i2];
            float dn = aa + b2 + 1e-9f;
            gateW[b * 2 + 0] = aa / dn;
            gateW[b * 2 + 1] = b2 / dn;
            gateI[b * 2 + 0] = i1;
            gateI[b * 2 + 1] = i2;
        }
    }
    __threadfence();
    grid.sync();

    // ================= P4: gated expert conv stats (2 slots) ===============
    const int e1 = gateI[b * 2 + 0], e2 = gateI[b * 2 + 1];
    {
        s16x8 afr1[3], afr2[3];
        ldafr(wsf + SH_EWF + ((size_t)((1 + e1) * 8 + g) * 3) * 64 * 8, l, afr1);
        ldafr(wsf + SH_EWF + ((size_t)((1 + e2) * 8 + g) * 3) * 64 * 8, l, afr2);
        float b1[4], b2a[4];
        #pragma unroll
        for (int r = 0; r < 4; ++r) {
            b1[r]  = eb[e1 * 128 + g * CPG + grp * 4 + r];
            b2a[r] = eb[e2 * 128 + g * CPG + grp * 4 + r];
        }
        float s1 = 0.f, q1 = 0.f, s2 = 0.f, q2 = 0.f;
        for (int tile = 0; tile < 16; ++tile) {
            const int t0 = (wv * 16 + tile) * 16;
            s16x8 bf0 = *(const s16x8*)&xs[(t0 + n + 0 + s_) * ROWS + cib];
            s16x8 bf1 = *(const s16x8*)&xs[(t0 + n + 2 + s_) * ROWS + cib];
            s16x8 bf2 = *(const s16x8*)&xs[(t0 + n + 4 + s_) * ROWS + cib];
            f32x4 c1 = {0.f, 0.f, 0.f, 0.f};
            c1 = __builtin_amdgcn_mfma_f32_16x16x32_bf16(afr1[0], bf0, c1, 0, 0, 0);
            c1 = __builtin_amdgcn_mfma_f32_16x16x32_bf16(afr1[1], bf1, c1, 0, 0, 0);
            c1 = __builtin_amdgcn_mfma_f32_16x16x32_bf16(afr1[2], bf2, c1, 0, 0, 0);
            f32x4 c2 = {0.f, 0.f, 0.f, 0.f};
            c2 = __builtin_amdgcn_mfma_f32_16x16x32_bf16(afr2[0], bf0, c2, 0, 0, 0);
            c2 = __builtin_amdgcn_mfma_f32_16x16x32_bf16(afr2[1], bf1, c2, 0, 0, 0);
            c2 = __builtin_amdgcn_mfma_f32_16x16x32_bf16(afr2[2], bf2, c2, 0, 0, 0);
            #pragma unroll
            for (int r = 0; r < 4; ++r) {
                float v1 = c1[r] + b1[r];  s1 += v1; q1 += v1 * v1;
                float v2 = c2[r] + b2a[r]; s2 += v2; q2 += v2 * v2;
            }
        }
        for (int d = 1; d < 64; d <<= 1) {
            s1 += __shfl_xor(s1, d); q1 += __shfl_xor(q1, d);
            s2 += __shfl_xor(s2, d); q2 += __shfl_xor(q2, d);
        }
        if (l == 0) {
            int base = ((b * NG + g) * 2) * 8 + h * 4 + wv;
            ste[base * 2 + 0] = s1; ste[base * 2 + 1] = q1;
            int base2 = ((b * NG + g) * 2 + 1) * 8 + h * 4 + wv;
            ste[base2 * 2 + 0] = s2; ste[base2 * 2 + 1] = q2;
        }
    }
    __threadfence();
    grid.sync();

    // ================= P5: fold + conv recompute + epilogue + store ========
    {
        const float scl[3] = {1.0f, gateW[b * 2 + 0], gateW[b * 2 + 1]};
        s16x8 afr[3][3];
        ldafr(wsf + SH_EWF + ((size_t)(0 * 8 + g) * 3) * 64 * 8, l, afr[0]);
        ldafr(wsf + SH_EWF + ((size_t)((1 + e1) * 8 + g) * 3) * 64 * 8, l, afr[1]);
        ldafr(wsf + SH_EWF + ((size_t)((1 + e2) * 8 + g) * 3) * 64 * 8, l, afr[2]);

        const float inv_n = 1.0f / (CPG * T_);
        float ka[3][4], kb[3][4];
        #pragma unroll
        for (int sl = 0; sl < 3; ++sl) {
            const float* sp = (sl == 0) ? stsh + (size_t)(b * NG + g) * 16
                                        : ste + (((size_t)(b * NG + g) * 2 + (sl - 1)) * 8) * 2;
            float S = 0.f, Q = 0.f;
            for (int i = 0; i < 8; ++i) { S += sp[i * 2]; Q += sp[i * 2 + 1]; }
            float mu = S * inv_n;
            float rs = rsqrtf(Q * inv_n - mu * mu + EPS_);
            int e = (sl == 1) ? e1 : e2;
            const float* bs = (sl == 0) ? sb  : eb  + e * 128;
            const float* gs = (sl == 0) ? sg  : eg  + e * 128;
            const float* bt = (sl == 0) ? sbt : ebt + e * 128;
            #pragma unroll
            for (int r = 0; r < 4; ++r) {
                int co = g * CPG + grp * 4 + r;
                float gm = gs[co];
                ka[sl][r] = rs * gm;
                kb[sl][r] = (bs[co] - mu) * rs * gm + bt[co];
            }
        }

        for (int tile = 0; tile < 16; ++tile) {
            const int t0 = (wv * 16 + tile) * 16;
            s16x8 bf0 = *(const s16x8*)&xs[(t0 + n + 0 + s_) * ROWS + cib];
            s16x8 bf1 = *(const s16x8*)&xs[(t0 + n + 2 + s_) * ROWS + cib];
            s16x8 bf2 = *(const s16x8*)&xs[(t0 + n + 4 + s_) * ROWS + cib];
            f32x4 oacc = {0.f, 0.f, 0.f, 0.f};
            #pragma unroll
            for (int sl = 0; sl < 3; ++sl) {
                f32x4 cc = {0.f, 0.f, 0.f, 0.f};
                cc = __builtin_amdgcn_mfma_f32_16x16x32_bf16(afr[sl][0], bf0, cc, 0, 0, 0);
                cc = __builtin_amdgcn_mfma_f32_16x16x32_bf16(afr[sl][1], bf1, cc, 0, 0, 0);
                cc = __builtin_amdgcn_mfma_f32_16x16x32_bf16(afr[sl][2], bf2, cc, 0, 0, 0);
                #pragma unroll
                for (int r = 0; r < 4; ++r)
                    oacc[r] += scl[sl] * gelu_sig(cc[r] * ka[sl][r] + kb[sl][r]);
            }
            size_t obase = ((size_t)(b * HID + g * CPG + grp * 4)) * T_
                         + h * QT + t0 + n;
            #pragma unroll
            for (int r = 0; r < 4; ++r)
                out[obase + (size_t)r * T_] = oacc[r];
        }
    }
}

// ---------------------------------------------------------------------------
extern "C" void kernel_launch(void* const* d_in, const int* in_sizes, int n_in,
                              void* d_out, int out_size, void* d_ws, size_t ws_size,
                              hipStream_t stream)
{
    const float* x    = (const float*)d_in[0];
    const float* demo = (const float*)d_in[1];
    const float* rw   = (const float*)d_in[2];
    const float* rg   = (const float*)d_in[3];
    const float* rb   = (const float*)d_in[4];
    const float* m1w  = (const float*)d_in[5];
    const float* m1b  = (const float*)d_in[6];
    const float* lng  = (const float*)d_in[7];
    const float* lnb  = (const float*)d_in[8];
    const float* m2w  = (const float*)d_in[9];
    const float* m2b  = (const float*)d_in[10];
    const float* d1w  = (const float*)d_in[11];
    const float* d1b  = (const float*)d_in[12];
    const float* dlng = (const float*)d_in[13];
    const float* dlnb = (const float*)d_in[14];
    const float* d2w  = (const float*)d_in[15];
    const float* d2b  = (const float*)d_in[16];
    const float* gw   = (const float*)d_in[17];
    const float* gb   = (const float*)d_in[18];
    const float* ew   = (const float*)d_in[19];
    const float* eb   = (const float*)d_in[20];
    const float* eg   = (const float*)d_in[21];
    const float* ebt  = (const float*)d_in[22];
    const float* sw   = (const float*)d_in[23];
    const float* sb   = (const float*)d_in[24];
    const float* sg   = (const float*)d_in[25];
    const float* sbt  = (const float*)d_in[26];
    float* out = (float*)d_out;
    short* wsfs = (short*)d_ws;

    void* args[] = {
        (void*)&x, (void*)&rw, (void*)&ew, (void*)&sw,
        (void*)&rg, (void*)&rb, (void*)&demo,
        (void*)&m1w, (void*)&m1b, (void*)&lng, (void*)&lnb,
        (void*)&m2w, (void*)&m2b,
        (void*)&d1w, (void*)&d1b, (void*)&dlng, (void*)&dlnb,
        (void*)&d2w, (void*)&d2b, (void*)&gw, (void*)&gb,
        (void*)&eb, (void*)&eg, (void*)&ebt,
        (void*)&sb, (void*)&sg, (void*)&sbt,
        (void*)&wsfs, (void*)&out
    };
    dim3 grid(B_, NG, NH);
    dim3 blk(256);
    hipLaunchCooperativeKernel((void*)fused_kernel, grid, blk, args, 0, stream);
    (void)in_sizes; (void)n_in; (void)out_size; (void)ws_size;
}

// Round 14
// 44.425 us; speedup vs baseline: 11.8352x; 11.8352x over previous
//
#include <hip/hip_runtime.h>
#include <math.h>

#define B_    32
#define CIN   16
#define T_    2048
#define NG    8
#define CPG   16
#define HID   128
#define KW    5
#define EPS_  1e-5f

#define NROW  2080   // xT rows r = t+2; rows 0,1 and 2050..2079 zero
#define ROWS  16     // shorts per row (= CIN) -> 32B rows
#define NQ    4      // T quarters for expert kernels
#define QT    512    // t per quarter
#define QROWS 544    // staged rows per quarter

// ws layout: shorts
#define SH_EWF  1064960          // [es(0=sh,1..8)][g][p<3][l<64][8]
#define SH_RWF  1175552          // [g][p<3][l<64][8]
// floats (byte 2,375,680 onward)
#define FO_R0   593920           // r0 [32][128]
#define FO_GW   598016           // gate weights [64]
#define FO_GI   598080           // gate indices [64] (ints)
#define FO_STE  598144           // [(b*8+g)*2+sl][16] float2 (e1,e2 partials)
#define FO_STSH 614528           // [(b*8+g)] float2 (shared slot, complete)

typedef float f32x4 __attribute__((ext_vector_type(4)));
typedef short s16x8 __attribute__((ext_vector_type(8)));

__device__ __forceinline__ float gelu_fast(float y) {
    float p = y * y;
    float u = y * (0.7978845608028654f + 0.03567740813636141f * p);
    float au = fabsf(u);
    float e = __expf(2.0f * au);
    float th = copysignf(1.0f - 2.0f * __builtin_amdgcn_rcpf(e + 1.0f), u);
    return 0.5f * y * (1.0f + th);
}

__device__ __forceinline__ float gelu_sig(float y) {
    float e = __expf(-1.702f * y);
    return y * __builtin_amdgcn_rcpf(1.0f + e);
}

__device__ __forceinline__ float gelu_erf(float y) {
    return 0.5f * y * (1.0f + erff(y * 0.70710678118654752440f));
}

__device__ __forceinline__ short bf16r(float f) {
    unsigned u = __builtin_bit_cast(unsigned, f);
    u = u + 0x7FFFu + ((u >> 16) & 1u);
    return (short)(u >> 16);
}

// ---------------------------------------------------------------------------
// K0: fused prep. blocks 0..63: x -> xT bf16 transpose. blocks 64..143:
// weights -> bf16 MFMA-fragment layout.
// ---------------------------------------------------------------------------
__global__ __launch_bounds__(256) void prep_kernel(
    const float* __restrict__ x, const float* __restrict__ rw,
    const float* __restrict__ ew, const float* __restrict__ sw,
    short* __restrict__ wsf)
{
    const int bid = blockIdx.x, tid = threadIdx.x;
    if (bid < 64) {
        const int b = bid >> 1, half = bid & 1;
        const float* xb = x + (size_t)b * CIN * T_;
        short* xtb = wsf + (size_t)b * NROW * ROWS;
        const int t0 = (half * 256 + tid) * 4;

        float v[CIN][4];
        #pragma unroll
        for (int ci = 0; ci < CIN; ++ci)
            *(f32x4*)v[ci] = *(const f32x4*)(xb + ci * T_ + t0);

        #pragma unroll
        for (int tt = 0; tt < 4; ++tt) {
            s16x8 lo, hi;
            #pragma unroll
            for (int ci = 0; ci < 8; ++ci) lo[ci] = bf16r(v[ci][tt]);
            #pragma unroll
            for (int ci = 0; ci < 8; ++ci) hi[ci] = bf16r(v[ci + 8][tt]);
            short* rp = xtb + (size_t)(t0 + tt + 2) * ROWS;
            *(s16x8*)rp = lo;
            *(s16x8*)(rp + 8) = hi;
        }
        if (half == 0 && tid < 32) {
            int r = (tid < 2) ? tid : 2048 + tid;
            s16x8 z = {0, 0, 0, 0, 0, 0, 0, 0};
            short* rp = xtb + (size_t)r * ROWS;
            *(s16x8*)rp = z;
            *(s16x8*)(rp + 8) = z;
        }
    } else if (tid < 64) {
        const int id = bid - 64, l = tid;
        const int n = l & 15, grp = l >> 4;
        const int s_ = grp >> 1, cib = (grp & 1) * 8;
        const float* src;
        short* dst;
        if (id < 72) {
            int es = id / 8, g = id - es * 8;
            src = ((es == 0) ? sw : ew + (size_t)(es - 1) * 128 * (CIN * KW))
                  + (size_t)g * CPG * (CIN * KW);
            dst = wsf + SH_EWF + ((size_t)(es * 8 + g) * 3) * 64 * 8;
        } else {
            int g = id - 72;
            src = rw + (size_t)g * CPG * (CIN * KW);
            dst = wsf + SH_RWF + ((size_t)g * 3) * 64 * 8;
        }
        #pragma unroll
        for (int p = 0; p < 3; ++p) {
            int sh = 2 * p + s_;
            s16x8 a;
            if (sh < 5) {
                const float* wp = src + (size_t)n * (CIN * KW) + cib * KW + sh;
                #pragma unroll
                for (int j = 0; j < 8; ++j) a[j] = bf16r(wp[j * KW]);
            } else {
                #pragma unroll
                for (int j = 0; j < 8; ++j) a[j] = 0;
            }
            *(s16x8*)(dst + ((size_t)p * 64 + l) * 8) = a;
        }
    }
}

// stage xT[b] full (4160 x 16B) -> LDS (512 thr)
__device__ __forceinline__ void stage_xt_full(const short* __restrict__ xtb,
                                              short* __restrict__ xs, int tid)
{
    const s16x8* src = (const s16x8*)xtb;
    s16x8* dst = (s16x8*)xs;
    #pragma unroll
    for (int i = 0; i < 8; ++i)
        dst[tid + i * 512] = src[tid + i * 512];
    int i8 = tid + 8 * 512;
    if (i8 < NROW * 2) dst[i8] = src[i8];
}

// stage one T-quarter (QROWS x 32B = 1088 x 16B) -> LDS (256 thr)
__device__ __forceinline__ void stage_xt_q(const short* __restrict__ xtq,
                                           short* __restrict__ xs, int tid)
{
    const s16x8* src = (const s16x8*)xtq;
    s16x8* dst = (s16x8*)xs;
    #pragma unroll
    for (int i = 0; i < 4; ++i)
        dst[tid + i * 256] = src[tid + i * 256];
    int i4 = tid + 4 * 256;
    if (i4 < QROWS * 2) dst[i4] = src[i4];
}

// ---------------------------------------------------------------------------
// K1: router conv -> GN -> GELU -> mean => r0, PLUS shared-expert GN stats
// (gate-independent). block=(b,g), 512 thr.
// ---------------------------------------------------------------------------
__global__ __launch_bounds__(512, 4) void router_conv_kernel(
    const short* __restrict__ xt, const short* __restrict__ wsf,
    const float* __restrict__ rg, const float* __restrict__ rb,
    const float* __restrict__ sb,
    float* __restrict__ r0, float* __restrict__ stsh)
{
    __shared__ short xs[NROW * ROWS];
    __shared__ float redS[8], redQ[8], redSS[8], redQS[8];
    __shared__ float rsum[8][CPG];

    const int b = blockIdx.x, g = blockIdx.y;
    const int tid = threadIdx.x;
    const int l = tid & 63, wv = tid >> 6;
    const int n = l & 15, grp = l >> 4;
    const int s_ = grp >> 1;

    stage_xt_full(xt + (size_t)b * NROW * ROWS, xs, tid);

    const short* rwb = wsf + SH_RWF + ((size_t)g * 3) * 64 * 8;
    s16x8 afr0 = *(const s16x8*)(rwb + (0 * 64 + l) * 8);
    s16x8 afr1 = *(const s16x8*)(rwb + (1 * 64 + l) * 8);
    s16x8 afr2 = *(const s16x8*)(rwb + (2 * 64 + l) * 8);
    const short* swb = wsf + SH_EWF + ((size_t)(0 * 8 + g) * 3) * 64 * 8;
    s16x8 asr0 = *(const s16x8*)(swb + (0 * 64 + l) * 8);
    s16x8 asr1 = *(const s16x8*)(swb + (1 * 64 + l) * 8);
    s16x8 asr2 = *(const s16x8*)(swb + (2 * 64 + l) * 8);
    float bsh[4];
    #pragma unroll
    for (int r = 0; r < 4; ++r) bsh[r] = sb[g * CPG + grp * 4 + r];
    __syncthreads();

    const int cib = (grp & 1) * 8;
    f32x4 cst[16];
    float sA = 0.f, qA = 0.f, sS = 0.f, qS = 0.f;
    #pragma unroll
    for (int tile = 0; tile < 16; ++tile) {
        const int t0 = (wv * 16 + tile) * 16;
        s16x8 bf0 = *(const s16x8*)&xs[(t0 + n + 0 + s_) * ROWS + cib];
        s16x8 bf1 = *(const s16x8*)&xs[(t0 + n + 2 + s_) * ROWS + cib];
        s16x8 bf2 = *(const s16x8*)&xs[(t0 + n + 4 + s_) * ROWS + cib];
        f32x4 c = {0.f, 0.f, 0.f, 0.f};
        c = __builtin_amdgcn_mfma_f32_16x16x32_bf16(afr0, bf0, c, 0, 0, 0);
        c = __builtin_amdgcn_mfma_f32_16x16x32_bf16(afr1, bf1, c, 0, 0, 0);
        c = __builtin_amdgcn_mfma_f32_16x16x32_bf16(afr2, bf2, c, 0, 0, 0);
        cst[tile] = c;
        f32x4 cs = {0.f, 0.f, 0.f, 0.f};
        cs = __builtin_amdgcn_mfma_f32_16x16x32_bf16(asr0, bf0, cs, 0, 0, 0);
        cs = __builtin_amdgcn_mfma_f32_16x16x32_bf16(asr1, bf1, cs, 0, 0, 0);
        cs = __builtin_amdgcn_mfma_f32_16x16x32_bf16(asr2, bf2, cs, 0, 0, 0);
        #pragma unroll
        for (int r = 0; r < 4; ++r) {
            sA += c[r]; qA += c[r] * c[r];
            float v = cs[r] + bsh[r];
            sS += v; qS += v * v;
        }
    }

    for (int d = 1; d < 64; d <<= 1) {
        sA += __shfl_xor(sA, d); qA += __shfl_xor(qA, d);
        sS += __shfl_xor(sS, d); qS += __shfl_xor(qS, d);
    }
    if (l == 0) {
        redS[wv] = sA; redQ[wv] = qA;
        redSS[wv] = sS; redQS[wv] = qS;
    }
    __syncthreads();
    float S = 0.f, Q = 0.f;
    for (int i = 0; i < 8; ++i) { S += redS[i]; Q += redQ[i]; }
    if (tid == 0) {
        float SS = 0.f, QS = 0.f;
        for (int i = 0; i < 8; ++i) { SS += redSS[i]; QS += redQS[i]; }
        stsh[(b * NG + g) * 2 + 0] = SS;
        stsh[(b * NG + g) * 2 + 1] = QS;
    }
    const float inv_n = 1.0f / (CPG * T_);
    float mu = S * inv_n;
    float rs = rsqrtf(Q * inv_n - mu * mu + EPS_);
    float ka[4], kb[4];
    #pragma unroll
    for (int r = 0; r < 4; ++r) {
        int co = g * CPG + grp * 4 + r;
        float gm = rg[co];
        ka[r] = rs * gm;
        kb[r] = rb[co] - mu * rs * gm;
    }

    f32x4 tacc = {0.f, 0.f, 0.f, 0.f};
    #pragma unroll
    for (int tile = 0; tile < 16; ++tile) {
        #pragma unroll
        for (int r = 0; r < 4; ++r)
            tacc[r] += gelu_fast(cst[tile][r] * ka[r] + kb[r]);
    }
    #pragma unroll
    for (int r = 0; r < 4; ++r)
        for (int d = 1; d < 16; d <<= 1)
            tacc[r] += __shfl_xor(tacc[r], d);
    if (n == 0) {
        #pragma unroll
        for (int r = 0; r < 4; ++r) rsum[wv][grp * 4 + r] = tacc[r];
    }
    __syncthreads();
    if (tid < CPG) {
        float a = 0.f;
        for (int w = 0; w < 8; ++w) a += rsum[w][tid];
        r0[b * HID + g * CPG + tid] = a * (1.0f / T_);
    }
}

// ---------------------------------------------------------------------------
// K2: router MLP + demo embedder + gate + softmax + top-2  (block per b)
// ---------------------------------------------------------------------------
__global__ void router_gate_kernel(
    const float* __restrict__ r0, const float* __restrict__ demo,
    const float* __restrict__ m1w, const float* __restrict__ m1b,
    const float* __restrict__ lng, const float* __restrict__ lnb,
    const float* __restrict__ m2w, const float* __restrict__ m2b,
    const float* __restrict__ d1w, const float* __restrict__ d1b,
    const float* __restrict__ dlng, const float* __restrict__ dlnb,
    const float* __restrict__ d2w, const float* __restrict__ d2b,
    const float* __restrict__ gw, const float* __restrict__ gb,
    float* __restrict__ gateW, int* __restrict__ gateI)
{
    __shared__ float sh[128];
    __shared__ float dd[32];
    __shared__ float rr[80];
    __shared__ float glds[8];
    __shared__ float red[2], redq[2];

    const int b = blockIdx.x;
    const int j = threadIdx.x;
    const int lane = j & 63, wv = j >> 6;

    sh[j] = r0[b * HID + j];
    __syncthreads();

    float v = m1b[j];
    for (int i = 0; i < 128; ++i) v += sh[i] * m1w[j * 128 + i];
    float s = v, sq = v * v;
    for (int d = 1; d < 64; d <<= 1) { s += __shfl_xor(s, d); sq += __shfl_xor(sq, d); }
    if (lane == 0) { red[wv] = s; redq[wv] = sq; }
    __syncthreads();
    float S = red[0] + red[1], SQ = redq[0] + redq[1];
    float mu = S * (1.f / 128.f), var = SQ * (1.f / 128.f) - mu * mu;
    float h = (v - mu) * rsqrtf(var + EPS_) * lng[j] + lnb[j];
    float gv = gelu_erf(h);
    __syncthreads();
    sh[j] = gv;
    __syncthreads();

    if (j < 64) {
        float rv = m2b[j];
        for (int i = 0; i < 128; ++i) rv += sh[i] * m2w[j * 128 + i];
        rr[j] = rv;
    } else if (j < 96) {
        int jd = j - 64;
        float u = d1b[jd];
        for (int i = 0; i < 8; ++i) u += demo[b * 8 + i] * d1w[jd * 8 + i];
        float s2 = u, q2 = u * u;
        for (int d = 1; d < 32; d <<= 1) { s2 += __shfl_xor(s2, d, 32); q2 += __shfl_xor(q2, d, 32); }
        float mu2 = s2 * (1.f / 32.f), var2 = q2 * (1.f / 32.f) - mu2 * mu2;
        float y = (u - mu2) * rsqrtf(var2 + EPS_) * dlng[jd] + dlnb[jd];
        dd[jd] = gelu_erf(y);
    }
    __syncthreads();
    if (j < 16) {
        float rv = d2b[j];
        for (int i = 0; i < 32; ++i) rv += dd[i] * d2w[j * 32 + i];
        rr[64 + j] = rv;
    }
    __syncthreads();
    if (j < 8) {
        float lg = gb[j];
        for (int i = 0; i < 80; ++i) lg += rr[i] * gw[j * 80 + i];
        glds[j] = lg;
    }
    __syncthreads();
    if (j == 0) {
        float wsf[8];
        float m = glds[0];
        for (int e = 1; e < 8; ++e) m = fmaxf(m, glds[e]);
        float ssum = 0.f;
        for (int e = 0; e < 8; ++e) { wsf[e] = expf(glds[e] - m); ssum += wsf[e]; }
        for (int e = 0; e < 8; ++e) wsf[e] /= ssum;
        int i1 = 0;
        for (int e = 1; e < 8; ++e) if (wsf[e] > wsf[i1]) i1 = e;
        int i2 = (i1 == 0) ? 1 : 0;
        for (int e = 0; e < 8; ++e) if (e != i1 && wsf[e] > wsf[i2]) i2 = e;
        float a = wsf[i1], b2 = wsf[i2];
        float dn = a + b2 + 1e-9f;
        gateW[b * 2 + 0] = a / dn;
        gateW[b * 2 + 1] = b2 / dn;
        gateI[b * 2 + 0] = i1;
        gateI[b * 2 + 1] = i2;
    }
}

// ---------------------------------------------------------------------------
// K3: expert conv stats (e1, e2 only) over one T-quarter. block=(b,g,q).
// ---------------------------------------------------------------------------
__global__ __launch_bounds__(256, 4) void expert_stats_kernel(
    const short* __restrict__ xt, const short* __restrict__ wsf,
    const float* __restrict__ eb,
    const int* __restrict__ gateI, float* __restrict__ ste)
{
    __shared__ short xs[QROWS * ROWS];

    const int b = blockIdx.x, g = blockIdx.y, q = blockIdx.z;
    const int tid = threadIdx.x;
    const int l = tid & 63, wv = tid >> 6;
    const int n = l & 15, grp = l >> 4;
    const int s_ = grp >> 1, cib = (grp & 1) * 8;

    const int e1 = gateI[b * 2 + 0], e2 = gateI[b * 2 + 1];

    stage_xt_q(xt + ((size_t)b * NROW + q * QT) * ROWS, xs, tid);

    s16x8 afr[2][3];
    const int esi[2] = {1 + e1, 1 + e2};
    #pragma unroll
    for (int sl = 0; sl < 2; ++sl) {
        const short* wb = wsf + SH_EWF + ((size_t)(esi[sl] * 8 + g) * 3) * 64 * 8;
        #pragma unroll
        for (int p = 0; p < 3; ++p)
            afr[sl][p] = *(const s16x8*)(wb + ((size_t)p * 64 + l) * 8);
    }
    float bia[2][4];
    #pragma unroll
    for (int sl = 0; sl < 2; ++sl) {
        const float* bs = eb + ((sl == 0) ? e1 : e2) * 128;
        #pragma unroll
        for (int r = 0; r < 4; ++r) bia[sl][r] = bs[g * CPG + grp * 4 + r];
    }
    __syncthreads();

    float sA[2] = {0.f, 0.f}, qA[2] = {0.f, 0.f};
    #pragma unroll 2
    for (int tile = 0; tile < 8; ++tile) {
        const int t0 = (wv * 8 + tile) * 16;
        s16x8 bf0 = *(const s16x8*)&xs[(t0 + n + 0 + s_) * ROWS + cib];
        s16x8 bf1 = *(const s16x8*)&xs[(t0 + n + 2 + s_) * ROWS + cib];
        s16x8 bf2 = *(const s16x8*)&xs[(t0 + n + 4 + s_) * ROWS + cib];
        #pragma unroll
        for (int sl = 0; sl < 2; ++sl) {
            f32x4 c = {0.f, 0.f, 0.f, 0.f};
            c = __builtin_amdgcn_mfma_f32_16x16x32_bf16(afr[sl][0], bf0, c, 0, 0, 0);
            c = __builtin_amdgcn_mfma_f32_16x16x32_bf16(afr[sl][1], bf1, c, 0, 0, 0);
            c = __builtin_amdgcn_mfma_f32_16x16x32_bf16(afr[sl][2], bf2, c, 0, 0, 0);
            #pragma unroll
            for (int r = 0; r < 4; ++r) {
                float v = c[r] + bia[sl][r];
                sA[sl] += v; qA[sl] += v * v;
            }
        }
    }
    #pragma unroll
    for (int sl = 0; sl < 2; ++sl)
        for (int d = 1; d < 64; d <<= 1) {
            sA[sl] += __shfl_xor(sA[sl], d);
            qA[sl] += __shfl_xor(qA[sl], d);
        }
    if (l == 0) {
        #pragma unroll
        for (int sl = 0; sl < 2; ++sl) {
            int idx = ((b * NG + g) * 2 + sl) * 16 + q * 4 + wv;
            ste[idx * 2 + 0] = sA[sl];
            ste[idx * 2 + 1] = qA[sl];
        }
    }
}

// ---------------------------------------------------------------------------
// K4: expert conv recompute over quarter -> folded GN + sig-GELU -> out.
// Shared stats from stsh (complete); e1/e2 stats folded from ste.
// ---------------------------------------------------------------------------
__global__ __launch_bounds__(256, 4) void expert_apply_kernel(
    const short* __restrict__ xt, const short* __restrict__ wsf,
    const float* __restrict__ eb, const float* __restrict__ eg,
    const float* __restrict__ ebt,
    const float* __restrict__ sb, const float* __restrict__ sg,
    const float* __restrict__ sbt,
    const float* __restrict__ gateW, const int* __restrict__ gateI,
    const float* __restrict__ ste, const float* __restrict__ stsh,
    float* __restrict__ out)
{
    __shared__ short xs[QROWS * ROWS];

    const int b = blockIdx.x, g = blockIdx.y, q = blockIdx.z;
    const int tid = threadIdx.x;
    const int l = tid & 63, wv = tid >> 6;
    const int n = l & 15, grp = l >> 4;
    const int s_ = grp >> 1, cib = (grp & 1) * 8;

    const int e1 = gateI[b * 2 + 0], e2 = gateI[b * 2 + 1];
    const float scl[3] = {1.0f, gateW[b * 2 + 0], gateW[b * 2 + 1]};

    stage_xt_q(xt + ((size_t)b * NROW + q * QT) * ROWS, xs, tid);

    s16x8 afr[3][3];
    const int esi[3] = {0, 1 + e1, 1 + e2};
    #pragma unroll
    for (int sl = 0; sl < 3; ++sl) {
        const short* wb = wsf + SH_EWF + ((size_t)(esi[sl] * 8 + g) * 3) * 64 * 8;
        #pragma unroll
        for (int p = 0; p < 3; ++p)
            afr[sl][p] = *(const s16x8*)(wb + ((size_t)p * 64 + l) * 8);
    }

    const float inv_n = 1.0f / (CPG * T_);
    float ka[3][4], kb[3][4];
    #pragma unroll
    for (int sl = 0; sl < 3; ++sl) {
        float S, Q;
        if (sl == 0) {
            S = stsh[(b * NG + g) * 2 + 0];
            Q = stsh[(b * NG + g) * 2 + 1];
        } else {
            S = 0.f; Q = 0.f;
            const float* sp = ste + (((size_t)(b * NG + g) * 2 + (sl - 1)) * 16) * 2;
            for (int i = 0; i < 16; ++i) { S += sp[i * 2]; Q += sp[i * 2 + 1]; }
        }
        float mu = S * inv_n;
        float rs = rsqrtf(Q * inv_n - mu * mu + EPS_);
        int e = (sl == 1) ? e1 : e2;
        const float* bs = (sl == 0) ? sb  : eb  + e * 128;
        const float* gs = (sl == 0) ? sg  : eg  + e * 128;
        const float* bt = (sl == 0) ? sbt : ebt + e * 128;
        #pragma unroll
        for (int r = 0; r < 4; ++r) {
            int co = g * CPG + grp * 4 + r;
            float gm = gs[co];
            ka[sl][r] = rs * gm;
            kb[sl][r] = (bs[co] - mu) * rs * gm + bt[co];
        }
    }
    __syncthreads();

    #pragma unroll 2
    for (int tile = 0; tile < 8; ++tile) {
        const int t0 = (wv * 8 + tile) * 16;
        s16x8 bf0 = *(const s16x8*)&xs[(t0 + n + 0 + s_) * ROWS + cib];
        s16x8 bf1 = *(const s16x8*)&xs[(t0 + n + 2 + s_) * ROWS + cib];
        s16x8 bf2 = *(const s16x8*)&xs[(t0 + n + 4 + s_) * ROWS + cib];
        f32x4 oacc = {0.f, 0.f, 0.f, 0.f};
        #pragma unroll
        for (int sl = 0; sl < 3; ++sl) {
            f32x4 c = {0.f, 0.f, 0.f, 0.f};
            c = __builtin_amdgcn_mfma_f32_16x16x32_bf16(afr[sl][0], bf0, c, 0, 0, 0);
            c = __builtin_amdgcn_mfma_f32_16x16x32_bf16(afr[sl][1], bf1, c, 0, 0, 0);
            c = __builtin_amdgcn_mfma_f32_16x16x32_bf16(afr[sl][2], bf2, c, 0, 0, 0);
            #pragma unroll
            for (int r = 0; r < 4; ++r)
                oacc[r] += scl[sl] * gelu_sig(c[r] * ka[sl][r] + kb[sl][r]);
        }
        size_t obase = ((size_t)(b * HID + g * CPG + grp * 4)) * T_
                     + q * QT + t0 + n;
        #pragma unroll
        for (int r = 0; r < 4; ++r)
            __builtin_nontemporal_store(oacc[r], &out[obase + (size_t)r * T_]);
    }
}

// ---------------------------------------------------------------------------
extern "C" void kernel_launch(void* const* d_in, const int* in_sizes, int n_in,
                              void* d_out, int out_size, void* d_ws, size_t ws_size,
                              hipStream_t stream)
{
    const float* x    = (const float*)d_in[0];
    const float* demo = (const float*)d_in[1];
    const float* rw   = (const float*)d_in[2];
    const float* rg   = (const float*)d_in[3];
    const float* rb   = (const float*)d_in[4];
    const float* m1w  = (const float*)d_in[5];
    const float* m1b  = (const float*)d_in[6];
    const float* lng  = (const float*)d_in[7];
    const float* lnb  = (const float*)d_in[8];
    const float* m2w  = (const float*)d_in[9];
    const float* m2b  = (const float*)d_in[10];
    const float* d1w  = (const float*)d_in[11];
    const float* d1b  = (const float*)d_in[12];
    const float* dlng = (const float*)d_in[13];
    const float* dlnb = (const float*)d_in[14];
    const float* d2w  = (const float*)d_in[15];
    const float* d2b  = (const float*)d_in[16];
    const float* gw   = (const float*)d_in[17];
    const float* gb   = (const float*)d_in[18];
    const float* ew   = (const float*)d_in[19];
    const float* eb   = (const float*)d_in[20];
    const float* eg   = (const float*)d_in[21];
    const float* ebt  = (const float*)d_in[22];
    const float* sw   = (const float*)d_in[23];
    const float* sb   = (const float*)d_in[24];
    const float* sg   = (const float*)d_in[25];
    const float* sbt  = (const float*)d_in[26];
    float* out = (float*)d_out;

    short* xt   = (short*)d_ws;
    short* wsfs = (short*)d_ws;
    float* wsff = (float*)d_ws;
    float* r0    = wsff + FO_R0;
    float* gateW = wsff + FO_GW;
    int*   gateI = (int*)wsff + FO_GI;
    float* ste   = wsff + FO_STE;
    float* stsh  = wsff + FO_STSH;

    prep_kernel<<<dim3(144), 256, 0, stream>>>(x, rw, ew, sw, wsfs);
    dim3 gridc(B_, NG);
    router_conv_kernel<<<gridc, 512, 0, stream>>>(xt, wsfs, rg, rb, sb, r0, stsh);
    router_gate_kernel<<<dim3(B_), 128, 0, stream>>>(
        r0, demo, m1w, m1b, lng, lnb, m2w, m2b,
        d1w, d1b, dlng, dlnb, d2w, d2b, gw, gb, gateW, gateI);
    dim3 gridq(B_, NG, NQ);
    expert_stats_kernel<<<gridq, 256, 0, stream>>>(xt, wsfs, eb, gateI, ste);
    expert_apply_kernel<<<gridq, 256, 0, stream>>>(
        xt, wsfs, eb, eg, ebt, sb, sg, sbt, gateW, gateI, ste, stsh, out);
    (void)in_sizes; (void)n_in; (void)out_size; (void)ws_size;
}